// Round 1
// baseline (128.183 us; speedup 1.0000x reference)
//
#include <hip/hip_runtime.h>
#include <math.h>

#define B_SZ 8192
#define HID 256
#define DIM 128
#define MAXN 64
#define KM 160     // key_net mid
#define DM 192     // decoder mid
#define SM 128     // size_pred mid
#define LN_EPS 1e-5f

// ---------------- Kernel A: keys[64][256] = tanh(LN(kW1 + kb1)) @ kW2 + kb2 ----------------
__global__ void __launch_bounds__(256) keys_kernel(
    const float* __restrict__ kW1, const float* __restrict__ kb1,
    const float* __restrict__ kg,  const float* __restrict__ kbe,
    const float* __restrict__ kW2, const float* __restrict__ kb2,
    float* __restrict__ keys)
{
    __shared__ float red[256];
    __shared__ float t_s[KM];
    const int j = blockIdx.x;
    const int tid = threadIdx.x;

    float v = 0.f;
    if (tid < KM) v = kW1[j * KM + tid] + kb1[tid];

    red[tid] = (tid < KM) ? v : 0.f;
    __syncthreads();
    for (int s = 128; s > 0; s >>= 1) {
        if (tid < s) red[tid] += red[tid + s];
        __syncthreads();
    }
    const float mu = red[0] / (float)KM;
    __syncthreads();

    const float d = (tid < KM) ? (v - mu) : 0.f;
    red[tid] = d * d;
    __syncthreads();
    for (int s = 128; s > 0; s >>= 1) {
        if (tid < s) red[tid] += red[tid + s];
        __syncthreads();
    }
    const float var = red[0] / (float)KM;
    const float rstd = rsqrtf(var + LN_EPS);

    if (tid < KM) t_s[tid] = tanhf(d * rstd * kg[tid] + kbe[tid]);
    __syncthreads();

    // each thread = one output column (256 cols)
    float acc = kb2[tid];
    #pragma unroll 4
    for (int k = 0; k < KM; ++k) acc = fmaf(t_s[k], kW2[k * HID + tid], acc);
    keys[j * HID + tid] = acc;
}

// ---------------- Kernel B: size_pred -> n_logits[B], n[B] ----------------
// one wave per batch row; lane c handles hidden cols c and c+64 (SM=128)
__global__ void __launch_bounds__(256) sizepred_kernel(
    const float* __restrict__ z,
    const float* __restrict__ sW1, const float* __restrict__ sb1,
    const float* __restrict__ sg,  const float* __restrict__ sbe,
    const float* __restrict__ sW2, const float* __restrict__ sb2,
    float* __restrict__ out_logits, float* __restrict__ out_nf,
    int* __restrict__ n_ws)
{
    __shared__ float z_s[4][HID];
    const int tid = threadIdx.x;
    const int w = tid >> 6, lane = tid & 63;
    const int b = blockIdx.x * 4 + w;

    // stage this wave's z row (256 f32 = 64 float4, one per lane)
    ((float4*)z_s[w])[lane] = ((const float4*)(z + (size_t)b * HID))[lane];

    float a0 = sb1[lane], a1 = sb1[64 + lane];
    #pragma unroll 4
    for (int k = 0; k < HID; ++k) {
        const float s = z_s[w][k];
        a0 = fmaf(s, sW1[k * SM + lane], a0);
        a1 = fmaf(s, sW1[k * SM + 64 + lane], a1);
    }

    // LayerNorm over the 128 hidden values (2 per lane across the wave)
    float sum = a0 + a1;
    #pragma unroll
    for (int off = 1; off < 64; off <<= 1) sum += __shfl_xor(sum, off, 64);
    const float mu = sum / (float)SM;
    const float d0 = a0 - mu, d1 = a1 - mu;
    float vs = d0 * d0 + d1 * d1;
    #pragma unroll
    for (int off = 1; off < 64; off <<= 1) vs += __shfl_xor(vs, off, 64);
    const float rstd = rsqrtf(vs / (float)SM + LN_EPS);

    float h0 = fmaf(d0 * rstd, sg[lane],      0.f) + sbe[lane];
    float h1 = fmaf(d1 * rstd, sg[64 + lane], 0.f) + sbe[64 + lane];
    h0 = fmaxf(h0, 0.f);
    h1 = fmaxf(h1, 0.f);

    float p = fmaf(h0, sW2[lane], h1 * sW2[64 + lane]);
    #pragma unroll
    for (int off = 1; off < 64; off <<= 1) p += __shfl_xor(p, off, 64);

    if (lane == 0) {
        const float logit = p + sb2[0];
        int n = (int)rintf(logit);          // round-half-to-even, matches jnp.round
        n = min(max(n, 0), MAXN - 1);
        out_logits[b] = logit;
        out_nf[b] = (float)n;
        n_ws[b] = n;
    }
}

// ---------------- Kernel D: zero-fill output + compute only valid (j < n[b]) rows ----------------
// one block (256 thr = 4 waves) per batch row b; block owns out0[b, :, :] (64*128 f32 = 32KB)
__global__ void __launch_bounds__(256) decoder_kernel(
    const float* __restrict__ z, const float* __restrict__ keys,
    const int* __restrict__ n_ws,
    const float* __restrict__ dW1, const float* __restrict__ db1,
    const float* __restrict__ dW2, const float* __restrict__ db2,
    float* __restrict__ out0)
{
    __shared__ float z_s[HID];
    __shared__ float h_s[4][DM];
    const int b = blockIdx.x;
    const int tid = threadIdx.x;
    const int w = tid >> 6, lane = tid & 63;

    float* orow = out0 + (size_t)b * (MAXN * DIM);   // 8192 floats
    float4* o4 = (float4*)orow;
    const float4 zf = make_float4(0.f, 0.f, 0.f, 0.f);
    #pragma unroll
    for (int i = 0; i < 8; ++i) o4[i * 256 + tid] = zf;   // 32KB contiguous zero-fill

    const int n = n_ws[b];
    if (n == 0) return;                                   // ~76% of blocks exit here

    if (tid < 64) ((float4*)z_s)[tid] = ((const float4*)(z + (size_t)b * HID))[tid];
    __syncthreads();  // orders zero-fill stores before compute overwrites + z_s visible

    // wave w handles rows j = w, w+4, ... (< n)
    for (int j = w; j < n; j += 4) {
        const float* __restrict__ key = keys + j * HID;
        float a0 = db1[lane], a1 = db1[64 + lane], a2 = db1[128 + lane];
        #pragma unroll 4
        for (int k = 0; k < HID; ++k) {
            const float s = z_s[k] * key[k];              // broadcast loads
            a0 = fmaf(s, dW1[k * DM + lane],       a0);
            a1 = fmaf(s, dW1[k * DM + 64 + lane],  a1);
            a2 = fmaf(s, dW1[k * DM + 128 + lane], a2);
        }
        h_s[w][lane]       = tanhf(a0);
        h_s[w][64 + lane]  = tanhf(a1);
        h_s[w][128 + lane] = tanhf(a2);
        // intra-wave LDS exchange: compiler orders ds_write -> ds_read via lgkmcnt
        float o0 = db2[lane], o1 = db2[64 + lane];
        #pragma unroll 4
        for (int k = 0; k < DM; ++k) {
            const float t = h_s[w][k];
            o0 = fmaf(t, dW2[k * DIM + lane],      o0);
            o1 = fmaf(t, dW2[k * DIM + 64 + lane], o1);
        }
        orow[j * DIM + lane]      = o0;
        orow[j * DIM + 64 + lane] = o1;
    }
}

extern "C" void kernel_launch(void* const* d_in, const int* in_sizes, int n_in,
                              void* d_out, int out_size, void* d_ws, size_t ws_size,
                              hipStream_t stream)
{
    const float* z   = (const float*)d_in[0];
    const float* kW1 = (const float*)d_in[1];
    const float* kb1 = (const float*)d_in[2];
    const float* kg  = (const float*)d_in[3];
    const float* kbe = (const float*)d_in[4];
    const float* kW2 = (const float*)d_in[5];
    const float* kb2 = (const float*)d_in[6];
    const float* dW1 = (const float*)d_in[7];
    const float* db1 = (const float*)d_in[8];
    const float* dW2 = (const float*)d_in[9];
    const float* db2 = (const float*)d_in[10];
    const float* sW1 = (const float*)d_in[11];
    const float* sb1 = (const float*)d_in[12];
    const float* sg  = (const float*)d_in[13];
    const float* sbe = (const float*)d_in[14];
    const float* sW2 = (const float*)d_in[15];
    const float* sb2 = (const float*)d_in[16];

    float* out0       = (float*)d_out;                         // [B, 64, 128]
    float* out_logits = out0 + (size_t)B_SZ * MAXN * DIM;      // [B, 1]
    float* out_nf     = out_logits + B_SZ;                     // [B] (written as float)

    float* keys = (float*)d_ws;                                // 64*256 f32 = 64KB
    int*   n_ws = (int*)((char*)d_ws + (size_t)MAXN * HID * sizeof(float)); // 32KB

    keys_kernel<<<MAXN, 256, 0, stream>>>(kW1, kb1, kg, kbe, kW2, kb2, keys);
    sizepred_kernel<<<B_SZ / 4, 256, 0, stream>>>(z, sW1, sb1, sg, sbe, sW2, sb2,
                                                  out_logits, out_nf, n_ws);
    decoder_kernel<<<B_SZ, 256, 0, stream>>>(z, keys, n_ws, dW1, db1, dW2, db2, out0);
}

// Round 2
// 117.376 us; speedup vs baseline: 1.0921x; 1.0921x over previous
//
#include <hip/hip_runtime.h>
#include <math.h>

#define B_SZ 8192
#define HID 256
#define DIM 128
#define MAXN 64
#define KM 160     // key_net mid
#define DM 192     // decoder mid
#define SM 128     // size_pred mid
#define LN_EPS 1e-5f

#define FILL_BLOCKS 2048
#define TOTAL_F4 ((size_t)B_SZ * MAXN * DIM / 4)          // 16,777,216 float4
#define F4_PER_THREAD (TOTAL_F4 / ((size_t)FILL_BLOCKS * 256))  // 32

// ---------------- Kernel A: zero-fill out0 + sizepred (blocks 0..2047) + keys (blocks 2048..2111) ----
__global__ void __launch_bounds__(256) fused_front_kernel(
    const float* __restrict__ z,
    const float* __restrict__ kW1, const float* __restrict__ kb1,
    const float* __restrict__ kg,  const float* __restrict__ kbe,
    const float* __restrict__ kW2, const float* __restrict__ kb2,
    const float* __restrict__ sW1, const float* __restrict__ sb1,
    const float* __restrict__ sg,  const float* __restrict__ sbe,
    const float* __restrict__ sW2, const float* __restrict__ sb2,
    float* __restrict__ out0, float* __restrict__ out_logits,
    float* __restrict__ out_nf, int* __restrict__ n_ws,
    float* __restrict__ keys)
{
    __shared__ float red[256];
    __shared__ float t_s[KM];
    __shared__ float z_s[4][HID];

    const int blk = blockIdx.x;
    const int tid = threadIdx.x;

    if (blk >= FILL_BLOCKS) {
        // ---- keys: j = blk - 2048 ----
        const int j = blk - FILL_BLOCKS;
        float v = 0.f;
        if (tid < KM) v = kW1[j * KM + tid] + kb1[tid];

        red[tid] = (tid < KM) ? v : 0.f;
        __syncthreads();
        for (int s = 128; s > 0; s >>= 1) {
            if (tid < s) red[tid] += red[tid + s];
            __syncthreads();
        }
        const float mu = red[0] / (float)KM;
        __syncthreads();

        const float d = (tid < KM) ? (v - mu) : 0.f;
        red[tid] = d * d;
        __syncthreads();
        for (int s = 128; s > 0; s >>= 1) {
            if (tid < s) red[tid] += red[tid + s];
            __syncthreads();
        }
        const float var = red[0] / (float)KM;
        const float rstd = rsqrtf(var + LN_EPS);

        if (tid < KM) t_s[tid] = tanhf(d * rstd * kg[tid] + kbe[tid]);
        __syncthreads();

        float acc = kb2[tid];
        #pragma unroll 4
        for (int k = 0; k < KM; ++k) acc = fmaf(t_s[k], kW2[k * HID + tid], acc);
        keys[j * HID + tid] = acc;
        return;
    }

    // ---- uniform grid-stride zero-fill of out0 (268 MB) ----
    {
        float4* o4 = (float4*)out0;
        const size_t g = (size_t)blk * 256 + tid;
        const float4 zf = make_float4(0.f, 0.f, 0.f, 0.f);
        #pragma unroll
        for (int i = 0; i < (int)F4_PER_THREAD; ++i)
            o4[(size_t)i * ((size_t)FILL_BLOCKS * 256) + g] = zf;
    }

    // ---- sizepred: 4 rows per block, wave per row ----
    const int w = tid >> 6, lane = tid & 63;
    const int b = blk * 4 + w;

    ((float4*)z_s[w])[lane] = ((const float4*)(z + (size_t)b * HID))[lane];

    float a0 = sb1[lane], a1 = sb1[64 + lane];
    #pragma unroll 4
    for (int k = 0; k < HID; ++k) {
        const float s = z_s[w][k];
        a0 = fmaf(s, sW1[k * SM + lane], a0);
        a1 = fmaf(s, sW1[k * SM + 64 + lane], a1);
    }

    float sum = a0 + a1;
    #pragma unroll
    for (int off = 1; off < 64; off <<= 1) sum += __shfl_xor(sum, off, 64);
    const float mu = sum / (float)SM;
    const float d0 = a0 - mu, d1 = a1 - mu;
    float vs = d0 * d0 + d1 * d1;
    #pragma unroll
    for (int off = 1; off < 64; off <<= 1) vs += __shfl_xor(vs, off, 64);
    const float rstd = rsqrtf(vs / (float)SM + LN_EPS);

    float h0 = d0 * rstd * sg[lane]      + sbe[lane];
    float h1 = d1 * rstd * sg[64 + lane] + sbe[64 + lane];
    h0 = fmaxf(h0, 0.f);
    h1 = fmaxf(h1, 0.f);

    float p = fmaf(h0, sW2[lane], h1 * sW2[64 + lane]);
    #pragma unroll
    for (int off = 1; off < 64; off <<= 1) p += __shfl_xor(p, off, 64);

    if (lane == 0) {
        const float logit = p + sb2[0];
        int n = (int)rintf(logit);          // round-half-even == jnp.round
        n = min(max(n, 0), MAXN - 1);
        out_logits[b] = logit;
        out_nf[b] = (float)n;
        n_ws[b] = n;
    }
}

// ---------------- Kernel B: compute valid rows; all 4 waves cooperate per row ----------------
__global__ void __launch_bounds__(256) decode_rows_kernel(
    const float* __restrict__ z, const float* __restrict__ keys,
    const int* __restrict__ n_ws,
    const float* __restrict__ dW1, const float* __restrict__ db1,
    const float* __restrict__ dW2, const float* __restrict__ db2,
    float* __restrict__ out0)
{
    const int b = blockIdx.x;
    const int n = n_ws[b];
    if (n == 0) return;                      // ~76% of blocks

    const int tid = threadIdx.x;
    const int w = tid >> 6, lane = tid & 63;

    __shared__ float z_s[HID];
    __shared__ float s_s[HID];               // zp row = z * keys[j]
    __shared__ float hp[4][DM];              // GEMV1 partials / tanh(h)
    __shared__ float op[4][DIM];             // GEMV2 partials

    if (tid < 64) ((float4*)z_s)[tid] = ((const float4*)(z + (size_t)b * HID))[tid];
    __syncthreads();

    float* orow = out0 + (size_t)b * (MAXN * DIM);

    for (int j = 0; j < n; ++j) {
        s_s[tid] = z_s[tid] * keys[j * HID + tid];
        __syncthreads();

        // GEMV1: h = s @ dW1 (+db1, tanh). wave w covers k in [64w, 64w+64)
        float a0 = 0.f, a1 = 0.f, a2 = 0.f;
        const int k0 = w * 64;
        #pragma unroll 4
        for (int kk = 0; kk < 64; ++kk) {
            const int k = k0 + kk;
            const float s = s_s[k];
            a0 = fmaf(s, dW1[k * DM + lane],       a0);
            a1 = fmaf(s, dW1[k * DM + 64 + lane],  a1);
            a2 = fmaf(s, dW1[k * DM + 128 + lane], a2);
        }
        hp[w][lane]       = a0;
        hp[w][64 + lane]  = a1;
        hp[w][128 + lane] = a2;
        __syncthreads();

        if (tid < DM) {
            const float h = hp[0][tid] + hp[1][tid] + hp[2][tid] + hp[3][tid] + db1[tid];
            hp[0][tid] = tanhf(h);
        }
        __syncthreads();

        // GEMV2: out = tanh(h) @ dW2 (+db2). wave w covers k in [48w, 48w+48)
        float o0 = 0.f, o1 = 0.f;
        const int k1 = w * 48;
        #pragma unroll 4
        for (int kk = 0; kk < 48; ++kk) {
            const int k = k1 + kk;
            const float t = hp[0][k];
            o0 = fmaf(t, dW2[k * DIM + lane],      o0);
            o1 = fmaf(t, dW2[k * DIM + 64 + lane], o1);
        }
        op[w][lane]      = o0;
        op[w][64 + lane] = o1;
        __syncthreads();

        if (tid < DIM) {
            orow[j * DIM + tid] = op[0][tid] + op[1][tid] + op[2][tid] + op[3][tid]
                                  + db2[tid];
        }
        __syncthreads();   // protect s_s/hp/op before next j
    }
}

extern "C" void kernel_launch(void* const* d_in, const int* in_sizes, int n_in,
                              void* d_out, int out_size, void* d_ws, size_t ws_size,
                              hipStream_t stream)
{
    const float* z   = (const float*)d_in[0];
    const float* kW1 = (const float*)d_in[1];
    const float* kb1 = (const float*)d_in[2];
    const float* kg  = (const float*)d_in[3];
    const float* kbe = (const float*)d_in[4];
    const float* kW2 = (const float*)d_in[5];
    const float* kb2 = (const float*)d_in[6];
    const float* dW1 = (const float*)d_in[7];
    const float* db1 = (const float*)d_in[8];
    const float* dW2 = (const float*)d_in[9];
    const float* db2 = (const float*)d_in[10];
    const float* sW1 = (const float*)d_in[11];
    const float* sb1 = (const float*)d_in[12];
    const float* sg  = (const float*)d_in[13];
    const float* sbe = (const float*)d_in[14];
    const float* sW2 = (const float*)d_in[15];
    const float* sb2 = (const float*)d_in[16];

    float* out0       = (float*)d_out;                         // [B, 64, 128]
    float* out_logits = out0 + (size_t)B_SZ * MAXN * DIM;      // [B, 1]
    float* out_nf     = out_logits + B_SZ;                     // [B]

    float* keys = (float*)d_ws;                                // 64*256 f32
    int*   n_ws = (int*)((char*)d_ws + (size_t)MAXN * HID * sizeof(float));

    fused_front_kernel<<<FILL_BLOCKS + MAXN, 256, 0, stream>>>(
        z, kW1, kb1, kg, kbe, kW2, kb2,
        sW1, sb1, sg, sbe, sW2, sb2,
        out0, out_logits, out_nf, n_ws, keys);

    decode_rows_kernel<<<B_SZ, 256, 0, stream>>>(z, keys, n_ws,
                                                 dW1, db1, dW2, db2, out0);
}